// Round 1
// baseline (460.062 us; speedup 1.0000x reference)
//
#include <hip/hip_runtime.h>

// ---------------------------------------------------------------------------
// OseroNetworks, round 3: slice-per-thread, LDS-free, fused single dispatch.
//
// Previous version staged 160B/element tiles through 44KB of LDS to fix the
// lane-stride scatter; that capped occupancy at 3 blocks/CU (29%) and created
// a stage->barrier->compute phase structure that left both pipes <31% busy.
//
// New decomposition: 4 threads per element, one slice each. Thread g handles
// element e=g>>2, slice s=g&3. Per-thread input is then CONTIGUOUS at byte
// offset g*40 (edge/corner, 5x dwordx2) and g*32 (cross, 2x dwordx4) -- the
// wave's loads cover a dense 2.5KB span with no LDS needed. All three MLPs
// are fused into one thread (registers reused phase-to-phase); the 4 slice
// partials combine with two __shfl_xor over width 4 and lane s==0 writes
// out[e] once: no memset, no atomics, one dispatch.
// Weights stay uniform-address -> scalar (SGPR) loads, math stays packed
// f32x2 (v_pk_fma_f32).
// ---------------------------------------------------------------------------

typedef float f2 __attribute__((ext_vector_type(2)));

// One 3-layer MLP over a single D-vector held in registers (xs = D/2 f2's).
template<int D>
__device__ __forceinline__ float mlp_slice(const f2* xs,
                                           const float* __restrict__ W1,
                                           const float* __restrict__ b1,
                                           const float* __restrict__ W2,
                                           const float* __restrict__ b2,
                                           const float* __restrict__ W3,
                                           const float* __restrict__ b3)
{
    constexpr int H = D / 2;

    f2 h1[H];                                   // outputs o = 2*op, 2*op+1
    #pragma unroll
    for (int op = 0; op < H; ++op) {
        f2 a = {b1[2 * op], b1[2 * op + 1]};
        #pragma unroll
        for (int i = 0; i < D; ++i) {
            const float xv = (i & 1) ? xs[i >> 1].y : xs[i >> 1].x;
            const f2 w = {W1[(2 * op) * D + i], W1[(2 * op + 1) * D + i]};
            a = __builtin_elementwise_fma(w, (f2){xv, xv}, a);
        }
        h1[op] = __builtin_elementwise_max(a, (f2){0.0f, 0.0f});
    }

    f2 h2[H];
    #pragma unroll
    for (int op = 0; op < H; ++op) {
        f2 a = {b2[2 * op], b2[2 * op + 1]};
        #pragma unroll
        for (int i = 0; i < D; ++i) {
            const float hv = (i & 1) ? h1[i >> 1].y : h1[i >> 1].x;
            const f2 w = {W2[(2 * op) * D + i], W2[(2 * op + 1) * D + i]};
            a = __builtin_elementwise_fma(w, (f2){hv, hv}, a);
        }
        h2[op] = __builtin_elementwise_max(a, (f2){0.0f, 0.0f});
    }

    f2 o = {0.0f, 0.0f};
    #pragma unroll
    for (int k = 0; k < H; ++k) {
        const f2 w3 = {W3[2 * k], W3[2 * k + 1]};
        o = __builtin_elementwise_fma(w3, h2[k], o);
    }
    return o.x + o.y + b3[0];                   // b3 applied once per slice
}

__global__ __launch_bounds__(256)
void osero_kernel(const float* __restrict__ edge,
                  const float* __restrict__ cross_,
                  const float* __restrict__ corner,
                  const float* __restrict__ cn,
                  const float* __restrict__ eW1, const float* __restrict__ eb1,
                  const float* __restrict__ eW2, const float* __restrict__ eb2,
                  const float* __restrict__ eW3, const float* __restrict__ eb3,
                  const float* __restrict__ xW1, const float* __restrict__ xb1,
                  const float* __restrict__ xW2, const float* __restrict__ xb2,
                  const float* __restrict__ xW3, const float* __restrict__ xb3,
                  const float* __restrict__ cW1, const float* __restrict__ cb1,
                  const float* __restrict__ cW2, const float* __restrict__ cb2,
                  const float* __restrict__ cW3, const float* __restrict__ cb3,
                  const float* __restrict__ nW,  const float* __restrict__ nb,
                  float* __restrict__ out, int nelem)
{
    const int g = blockIdx.x * 256 + threadIdx.x;   // slice-thread id
    const int e = g >> 2;                           // element
    const int s = g & 3;                            // slice within element
    if (e >= nelem) return;                         // uniform within each quad

    // -------- issue the whole input burst up front (pure VMEM, no LDS) -----
    // edge slice: 10 floats at byte offset g*40 (8B-aligned dwordx2 x5)
    f2 xe[5];
    {
        const f2* p = reinterpret_cast<const f2*>(edge) + (size_t)g * 5;
        #pragma unroll
        for (int k = 0; k < 5; ++k) xe[k] = p[k];
    }
    // corner slice: same layout
    f2 xq[5];
    {
        const f2* p = reinterpret_cast<const f2*>(corner) + (size_t)g * 5;
        #pragma unroll
        for (int k = 0; k < 5; ++k) xq[k] = p[k];
    }
    // cross slice: 8 floats at byte offset g*32 (16B-aligned dwordx4 x2)
    f2 xc[4];
    {
        const float4* p = reinterpret_cast<const float4*>(cross_) + (size_t)g * 2;
        const float4 v0 = p[0];
        const float4 v1 = p[1];
        xc[0] = (f2){v0.x, v0.y}; xc[1] = (f2){v0.z, v0.w};
        xc[2] = (f2){v1.x, v1.y}; xc[3] = (f2){v1.z, v1.w};
    }
    const float cnv = (s == 0) ? cn[e] : 0.0f;      // predicated 4B load

    // -------- compute: three sequential MLP phases, registers reused -------
    float val = mlp_slice<10>(xe, eW1, eb1, eW2, eb2, eW3, eb3);
    val      += mlp_slice<10>(xq, cW1, cb1, cW2, cb2, cW3, cb3);
    val      += mlp_slice<8> (xc, xW1, xb1, xW2, xb2, xW3, xb3);

    // -------- combine the 4 slice partials, one store per element ----------
    val += __shfl_xor(val, 1, 4);
    val += __shfl_xor(val, 2, 4);

    if (s == 0)
        out[e] = val + fmaf(cnv, nW[0], nb[0]);
}

extern "C" void kernel_launch(void* const* d_in, const int* in_sizes, int n_in,
                              void* d_out, int out_size, void* d_ws, size_t ws_size,
                              hipStream_t stream) {
    const float* edge   = (const float*)d_in[0];
    const float* cross_ = (const float*)d_in[1];
    const float* corner = (const float*)d_in[2];
    const float* cn     = (const float*)d_in[3];
    const float* eW1 = (const float*)d_in[4];
    const float* eb1 = (const float*)d_in[5];
    const float* eW2 = (const float*)d_in[6];
    const float* eb2 = (const float*)d_in[7];
    const float* eW3 = (const float*)d_in[8];
    const float* eb3 = (const float*)d_in[9];
    const float* xW1 = (const float*)d_in[10];
    const float* xb1 = (const float*)d_in[11];
    const float* xW2 = (const float*)d_in[12];
    const float* xb2 = (const float*)d_in[13];
    const float* xW3 = (const float*)d_in[14];
    const float* xb3 = (const float*)d_in[15];
    const float* cW1 = (const float*)d_in[16];
    const float* cb1 = (const float*)d_in[17];
    const float* cW2 = (const float*)d_in[18];
    const float* cb2 = (const float*)d_in[19];
    const float* cW3 = (const float*)d_in[20];
    const float* cb3 = (const float*)d_in[21];
    const float* nW  = (const float*)d_in[22];
    const float* nb  = (const float*)d_in[23];

    const int nelem = in_sizes[3];                  // cn is [B,1] -> B
    const int nthr  = nelem * 4;                    // one thread per slice
    const int nblk  = (nthr + 255) / 256;

    osero_kernel<<<dim3(nblk), 256, 0, stream>>>(edge, cross_, corner, cn,
                                                 eW1, eb1, eW2, eb2, eW3, eb3,
                                                 xW1, xb1, xW2, xb2, xW3, xb3,
                                                 cW1, cb1, cW2, cb2, cW3, cb3,
                                                 nW, nb, (float*)d_out, nelem);
}

// Round 2
// 456.316 us; speedup vs baseline: 1.0082x; 1.0082x over previous
//
#include <hip/hip_runtime.h>

// ---------------------------------------------------------------------------
// OseroNetworks, round 4: LDS-broadcast weights + 4-element amortization.
//
// Rounds 2 and 3 both plateaued at VALUBusy~30% regardless of occupancy.
// Root cause: every pk_fma consumes a fresh 8B of weights via s_load, but
// the ~620 weight floats don't fit in 112 SGPRs, so the compiler issues
// them in batches each terminated by a full s_waitcnt lgkmcnt(0) drain
// (SMEM returns are out-of-order). ~3000 stall cyc vs 556 compute cyc/wave.
//
// Fix:
//  * Stage all weights in LDS once per block (~2.4 KB), pre-paired into the
//    f2 layout pk_fma wants. Uniform-address ds_read = broadcast (no bank
//    conflicts), returns IN ORDER -> compiler uses fine-grained lgkmcnt(N).
//  * Each thread processes the same slice of FOUR quarter-strided elements,
//    so each weight read feeds 4 pk_fmas (weight traffic amortized 4x).
//    Data loads remain fully coalesced: float offset = g*10 + k*(B/4)*40.
//  * Still LDS-free for data, single dispatch, no atomics/memset.
// ---------------------------------------------------------------------------

typedef float f2 __attribute__((ext_vector_type(2)));

__device__ __forceinline__ f2 pk_fma(f2 a, f2 b, f2 c) {
    return __builtin_elementwise_fma(a, b, c);
}

// Pair-packers for staging: wp[op*D+i] = {W[2op][i], W[(2op+1)][i]}.
__device__ __forceinline__ f2 pr10(const float* __restrict__ W, int j) {
    const int op = j / 10, i = j - op * 10;
    return (f2){W[op * 20 + i], W[op * 20 + 10 + i]};
}
__device__ __forceinline__ f2 pr8(const float* __restrict__ W, int j) {
    const int op = j >> 3, i = j & 7;
    return (f2){W[op * 16 + i], W[op * 16 + 8 + i]};
}
__device__ __forceinline__ f2 prc(const float* __restrict__ p, int k) {
    return (f2){p[2 * k], p[2 * k + 1]};
}

struct SW {
    f2 eW1[50], eW2[50], cW1[50], cW2[50];   // 10-D layers, paired
    f2 xW1[32], xW2[32];                     // 8-D layers, paired
    f2 eW3[5], cW3[5], xW3[4];               // output rows, paired
    f2 eb1[5], eb2[5], cb1[5], cb2[5];       // 10-D biases, paired
    f2 xb1[4], xb2[4];                       // 8-D biases, paired
};

// 3-layer MLP over FOUR D-vectors sharing one weight set. Weight ds_reads
// amortize 4x; all indices compile-time (full unroll) -> pure registers.
template<int D>
__device__ __forceinline__ void mlp_quad(const f2 (&xs)[4][D / 2],
                                         const f2* __restrict__ w1p, const f2* __restrict__ b1p,
                                         const f2* __restrict__ w2p, const f2* __restrict__ b2p,
                                         const f2* __restrict__ w3p, const float b3v,
                                         float (&val)[4])
{
    constexpr int H = D / 2;

    f2 h1[4][H];
    #pragma unroll
    for (int op = 0; op < H; ++op) {
        const f2 b = b1p[op];
        f2 a[4] = {b, b, b, b};
        #pragma unroll
        for (int i = 0; i < D; ++i) {
            const f2 w = w1p[op * D + i];                  // one broadcast read
            #pragma unroll
            for (int e = 0; e < 4; ++e) {                  // ...four uses
                const float xv = (i & 1) ? xs[e][i >> 1].y : xs[e][i >> 1].x;
                a[e] = pk_fma(w, (f2){xv, xv}, a[e]);
            }
        }
        #pragma unroll
        for (int e = 0; e < 4; ++e)
            h1[e][op] = __builtin_elementwise_max(a[e], (f2){0.0f, 0.0f});
    }

    f2 h2[4][H];
    #pragma unroll
    for (int op = 0; op < H; ++op) {
        const f2 b = b2p[op];
        f2 a[4] = {b, b, b, b};
        #pragma unroll
        for (int i = 0; i < D; ++i) {
            const f2 w = w2p[op * D + i];
            #pragma unroll
            for (int e = 0; e < 4; ++e) {
                const float hv = (i & 1) ? h1[e][i >> 1].y : h1[e][i >> 1].x;
                a[e] = pk_fma(w, (f2){hv, hv}, a[e]);
            }
        }
        #pragma unroll
        for (int e = 0; e < 4; ++e)
            h2[e][op] = __builtin_elementwise_max(a[e], (f2){0.0f, 0.0f});
    }

    f2 o[4] = {{0.f, 0.f}, {0.f, 0.f}, {0.f, 0.f}, {0.f, 0.f}};
    #pragma unroll
    for (int k = 0; k < H; ++k) {
        const f2 w3 = w3p[k];
        #pragma unroll
        for (int e = 0; e < 4; ++e)
            o[e] = pk_fma(w3, h2[e][k], o[e]);
    }
    #pragma unroll
    for (int e = 0; e < 4; ++e)
        val[e] += o[e].x + o[e].y + b3v;
}

__global__ __launch_bounds__(256)
void osero_kernel(const float* __restrict__ edge,
                  const float* __restrict__ cross_,
                  const float* __restrict__ corner,
                  const float* __restrict__ cn,
                  const float* __restrict__ eW1, const float* __restrict__ eb1,
                  const float* __restrict__ eW2, const float* __restrict__ eb2,
                  const float* __restrict__ eW3, const float* __restrict__ eb3,
                  const float* __restrict__ xW1, const float* __restrict__ xb1,
                  const float* __restrict__ xW2, const float* __restrict__ xb2,
                  const float* __restrict__ xW3, const float* __restrict__ xb3,
                  const float* __restrict__ cW1, const float* __restrict__ cb1,
                  const float* __restrict__ cW2, const float* __restrict__ cb2,
                  const float* __restrict__ cW3, const float* __restrict__ cb3,
                  const float* __restrict__ nW,  const float* __restrict__ nb,
                  float* __restrict__ out, int q /* = nelem/4 */)
{
    __shared__ SW sw;
    const int t = threadIdx.x;

    // One-time cooperative weight staging (different waves take branches).
    if (t < 50) {
        sw.eW1[t] = pr10(eW1, t); sw.eW2[t] = pr10(eW2, t);
        sw.cW1[t] = pr10(cW1, t); sw.cW2[t] = pr10(cW2, t);
    } else if (t >= 64 && t < 96) {
        const int j = t - 64;
        sw.xW1[j] = pr8(xW1, j); sw.xW2[j] = pr8(xW2, j);
    } else if (t >= 128 && t < 133) {
        const int k = t - 128;
        sw.eW3[k] = prc(eW3, k); sw.cW3[k] = prc(cW3, k);
        sw.eb1[k] = prc(eb1, k); sw.eb2[k] = prc(eb2, k);
        sw.cb1[k] = prc(cb1, k); sw.cb2[k] = prc(cb2, k);
    } else if (t >= 192 && t < 196) {
        const int k = t - 192;
        sw.xW3[k] = prc(xW3, k);
        sw.xb1[k] = prc(xb1, k); sw.xb2[k] = prc(xb2, k);
    }
    __syncthreads();

    const int g = blockIdx.x * 256 + t;     // slice-thread id, g in [0, 4q)
    const int s = t & 3;                    // slice within element
    float val[4] = {0.f, 0.f, 0.f, 0.f};

    {   // edge: slice s of elements e0 + k*q; float offset g*10 + k*q*40
        f2 xs[4][5];
        #pragma unroll
        for (int k = 0; k < 4; ++k) {
            const f2* p = reinterpret_cast<const f2*>(edge)
                        + (size_t)g * 5 + (size_t)k * q * 20;
            #pragma unroll
            for (int j = 0; j < 5; ++j) xs[k][j] = p[j];
        }
        mlp_quad<10>(xs, sw.eW1, sw.eb1, sw.eW2, sw.eb2, sw.eW3, eb3[0], val);
    }
    {   // corner
        f2 xs[4][5];
        #pragma unroll
        for (int k = 0; k < 4; ++k) {
            const f2* p = reinterpret_cast<const f2*>(corner)
                        + (size_t)g * 5 + (size_t)k * q * 20;
            #pragma unroll
            for (int j = 0; j < 5; ++j) xs[k][j] = p[j];
        }
        mlp_quad<10>(xs, sw.cW1, sw.cb1, sw.cW2, sw.cb2, sw.cW3, cb3[0], val);
    }
    {   // cross: 16B-aligned dwordx4 pairs
        f2 xs[4][4];
        #pragma unroll
        for (int k = 0; k < 4; ++k) {
            const float4* p = reinterpret_cast<const float4*>(cross_)
                            + (size_t)g * 2 + (size_t)k * q * 8;
            const float4 v0 = p[0];
            const float4 v1 = p[1];
            xs[k][0] = (f2){v0.x, v0.y}; xs[k][1] = (f2){v0.z, v0.w};
            xs[k][2] = (f2){v1.x, v1.y}; xs[k][3] = (f2){v1.z, v1.w};
        }
        mlp_quad<8>(xs, sw.xW1, sw.xb1, sw.xW2, sw.xb2, sw.xW3, xb3[0], val);
    }

    // Combine the 4 slice partials (width-4 butterfly), one store per element.
    #pragma unroll
    for (int k = 0; k < 4; ++k) {
        val[k] += __shfl_xor(val[k], 1, 4);
        val[k] += __shfl_xor(val[k], 2, 4);
    }
    if (s == 0) {
        const float w0 = nW[0], b0 = nb[0];
        const int e0 = g >> 2;
        #pragma unroll
        for (int k = 0; k < 4; ++k) {
            const int e = e0 + k * q;
            out[e] = val[k] + fmaf(cn[e], w0, b0);
        }
    }
}

extern "C" void kernel_launch(void* const* d_in, const int* in_sizes, int n_in,
                              void* d_out, int out_size, void* d_ws, size_t ws_size,
                              hipStream_t stream) {
    const float* edge   = (const float*)d_in[0];
    const float* cross_ = (const float*)d_in[1];
    const float* corner = (const float*)d_in[2];
    const float* cn     = (const float*)d_in[3];
    const float* eW1 = (const float*)d_in[4];
    const float* eb1 = (const float*)d_in[5];
    const float* eW2 = (const float*)d_in[6];
    const float* eb2 = (const float*)d_in[7];
    const float* eW3 = (const float*)d_in[8];
    const float* eb3 = (const float*)d_in[9];
    const float* xW1 = (const float*)d_in[10];
    const float* xb1 = (const float*)d_in[11];
    const float* xW2 = (const float*)d_in[12];
    const float* xb2 = (const float*)d_in[13];
    const float* xW3 = (const float*)d_in[14];
    const float* xb3 = (const float*)d_in[15];
    const float* cW1 = (const float*)d_in[16];
    const float* cb1 = (const float*)d_in[17];
    const float* cW2 = (const float*)d_in[18];
    const float* cb2 = (const float*)d_in[19];
    const float* cW3 = (const float*)d_in[20];
    const float* cb3 = (const float*)d_in[21];
    const float* nW  = (const float*)d_in[22];
    const float* nb  = (const float*)d_in[23];

    const int nelem = in_sizes[3];          // cn is [B,1] -> B (divisible by 1024)
    const int q     = nelem / 4;            // elements per quarter
    const int nblk  = nelem / 256;          // one thread per (slice, 4 elements)

    osero_kernel<<<dim3(nblk), 256, 0, stream>>>(edge, cross_, corner, cn,
                                                 eW1, eb1, eW2, eb2, eW3, eb3,
                                                 xW1, xb1, xW2, xb2, xW3, xb3,
                                                 cW1, cb1, cW2, cb2, cW3, cb3,
                                                 nW, nb, (float*)d_out, q);
}